// Round 6
// baseline (231.643 us; speedup 1.0000x reference)
//
#include <hip/hip_runtime.h>

// HaloAttention. B=2, H=W=128, C=128, NH=4, hd=32, WS=16, HS=8, WSH=32.
// R6: key-split attention (8 waves/block: 4 query-groups x 2 key-halves,
// additive partial-(O,l) combine), shared Vt transpose, phased 32-key P LDS,
// bf16 bias fragments, exp2-domain softmax, x-read-once QKV GEMM.

typedef unsigned short ushort_t;
typedef __attribute__((ext_vector_type(8))) short bf16x8;
typedef __attribute__((ext_vector_type(4))) float floatx4;

#define NHEADS 4
#define BTBL 2209          // 47*47 bias table rows
#define PK 40              // P stride (bf16): 32 keys + 8 pad (mult of 8)
#define VK 72              // Vt stride (bf16): 64 keys + 8 pad (mult of 8)
// 2^-1.5 * log2(e)  (q scale folded with exp2-domain conversion)
#define QS_LOG2E 0.2550348635f
#define LOG2E 1.4426950408889634f

#if __has_builtin(__builtin_amdgcn_exp2f)
#define EXP2F(x) __builtin_amdgcn_exp2f(x)
#else
#define EXP2F(x) __expf((x) * 0.6931471805599453f)
#endif

__device__ __forceinline__ int reflect_idx(int p) {
    p = (p < 0) ? -p : p;
    p = (p > 127) ? 254 - p : p;
    return p;
}

// fp32 -> bf16 bits, RNE
__device__ __forceinline__ unsigned f2b(float x) {
    unsigned u = __float_as_uint(x);
    return (u + 0x7fffu + ((u >> 16) & 1u)) >> 16;
}

// ---------------------------------------------------------------------------
__global__ __launch_bounds__(256) void pack_w(
    const float* __restrict__ Wq, const float* __restrict__ Wk,
    const float* __restrict__ Wv, const float* __restrict__ Wp,
    const float* __restrict__ bq, const float* __restrict__ bk,
    const float* __restrict__ bv, const float* __restrict__ bp,
    ushort_t* __restrict__ Wqkv, ushort_t* __restrict__ Wpb,
    float* __restrict__ bqkv, float* __restrict__ bpb)
{
    int idx = blockIdx.x * 256 + threadIdx.x;
    if (idx < 16384)       Wqkv[idx] = (ushort_t)f2b(Wq[idx]);
    else if (idx < 32768)  Wqkv[idx] = (ushort_t)f2b(Wk[idx - 16384]);
    else if (idx < 49152)  Wqkv[idx] = (ushort_t)f2b(Wv[idx - 32768]);
    else if (idx < 65536)  Wpb[idx - 49152] = (ushort_t)f2b(Wp[idx - 49152]);
    else {
        int e = idx - 65536;
        for (int k = e; k < 512; k += 256) {
            if (k < 128)      bqkv[k] = bq[k];
            else if (k < 256) bqkv[k] = bk[k - 128];
            else if (k < 384) bqkv[k] = bv[k - 256];
            else              bpb[k - 384] = bp[k - 384];
        }
    }
}

// ---------------------------------------------------------------------------
// Bias fragments in bf16, pre-multiplied by log2(e):
// layout [h][kt 64][qt 16][lane 64][reg 4] (bf16).
__global__ __launch_bounds__(256) void bias_frag(
    const float* __restrict__ bt, ushort_t* __restrict__ bf)
{
    int idx = blockIdx.x * 256 + threadIdx.x;   // 4*64*16*64*4 = 4,194,304
    int reg  = idx & 3;
    int lane = (idx >> 2) & 63;
    int qt   = (idx >> 8) & 15;
    int kt   = (idx >> 12) & 63;
    int h    = idx >> 18;
    int key  = kt * 16 + ((lane >> 4) << 2) + reg;
    int q    = qt * 16 + (lane & 15);
    int kr = key >> 5, kc = key & 31;
    int bidx = ((q >> 5) + 31 - kr) * 47 + (q & 31) - kc + 23;
    if (bidx < 0) bidx += BTBL;
    bf[idx] = (ushort_t)f2b(bt[bidx * NHEADS + h] * LOG2E);
}

// ---------------------------------------------------------------------------
// QKV GEMM: reads x once per block, loops over the 3 output 128-col blocks.
// Q block (nb==0) scaled by 2^-1.5 * log2e. Output bf16 [pix][384].
__global__ __launch_bounds__(256) void gemm_qkv(
    const float* __restrict__ X, const ushort_t* __restrict__ W,
    const float* __restrict__ bias, ushort_t* __restrict__ Y)
{
    __shared__ ushort_t Xs[128 * 136];

    const int t    = threadIdx.x;
    const int w    = t >> 6;
    const int lane = t & 63;
    const int quad = lane >> 4;
    const int l15  = lane & 15;
    const int m0   = blockIdx.x * 128;

    #pragma unroll
    for (int i = 0; i < 16; ++i) {
        int s = t + i * 256;
        int row = s >> 5, c4 = s & 31;
        float4 v = *(const float4*)&X[(size_t)(m0 + row) * 128 + c4 * 4];
        uint2 pk;
        pk.x = f2b(v.x) | (f2b(v.y) << 16);
        pk.y = f2b(v.z) | (f2b(v.w) << 16);
        *(uint2*)&Xs[row * 136 + c4 * 4] = pk;
    }
    __syncthreads();

    for (int nb = 0; nb < 3; ++nb) {
        const float sc = (nb == 0) ? QS_LOG2E : 1.0f;
        floatx4 acc[2][8];
        #pragma unroll
        for (int nt = 0; nt < 8; ++nt) {
            float bb = bias[nb * 128 + nt * 16 + l15];
            acc[0][nt] = (floatx4)bb;
            acc[1][nt] = (floatx4)bb;
        }
        #pragma unroll
        for (int kc = 0; kc < 4; ++kc) {
            bf16x8 af[2], bfr[8];
            #pragma unroll
            for (int mt = 0; mt < 2; ++mt)
                af[mt] = *(const bf16x8*)&Xs[(w * 32 + mt * 16 + l15) * 136 + kc * 32 + quad * 8];
            #pragma unroll
            for (int nt = 0; nt < 8; ++nt)
                bfr[nt] = *(const bf16x8*)&W[(size_t)(nb * 128 + nt * 16 + l15) * 128 + kc * 32 + quad * 8];
            #pragma unroll
            for (int mt = 0; mt < 2; ++mt)
                #pragma unroll
                for (int nt = 0; nt < 8; ++nt)
                    acc[mt][nt] = __builtin_amdgcn_mfma_f32_16x16x32_bf16(af[mt], bfr[nt], acc[mt][nt], 0, 0, 0);
        }
        #pragma unroll
        for (int mt = 0; mt < 2; ++mt) {
            #pragma unroll
            for (int r = 0; r < 4; ++r) {
                int m = m0 + w * 32 + mt * 16 + quad * 4 + r;
                #pragma unroll
                for (int nt = 0; nt < 8; ++nt) {
                    int n = nb * 128 + nt * 16 + l15;
                    Y[(size_t)m * 384 + n] = (ushort_t)f2b(acc[mt][nt][r] * sc);
                }
            }
        }
    }
}

// ---------------------------------------------------------------------------
// Projection GEMM: bf16 in (attention output), fp32 out.
__global__ __launch_bounds__(256) void gemm_proj(
    const ushort_t* __restrict__ X, const ushort_t* __restrict__ W,
    const float* __restrict__ bias, float* __restrict__ Y)
{
    __shared__ ushort_t Xs[128 * 136];

    const int t    = threadIdx.x;
    const int w    = t >> 6;
    const int lane = t & 63;
    const int quad = lane >> 4;
    const int l15  = lane & 15;
    const int m0   = blockIdx.x * 128;

    #pragma unroll
    for (int i = 0; i < 8; ++i) {
        int s = t + i * 256;
        int row = s >> 4, c8 = s & 15;
        *(int4*)&Xs[row * 136 + c8 * 8] = *(const int4*)&X[(size_t)(m0 + row) * 128 + c8 * 8];
    }
    __syncthreads();

    floatx4 acc[2][8];
    #pragma unroll
    for (int nt = 0; nt < 8; ++nt) {
        float bb = bias[nt * 16 + l15];
        acc[0][nt] = (floatx4)bb;
        acc[1][nt] = (floatx4)bb;
    }
    #pragma unroll
    for (int kc = 0; kc < 4; ++kc) {
        bf16x8 af[2], bfr[8];
        #pragma unroll
        for (int mt = 0; mt < 2; ++mt)
            af[mt] = *(const bf16x8*)&Xs[(w * 32 + mt * 16 + l15) * 136 + kc * 32 + quad * 8];
        #pragma unroll
        for (int nt = 0; nt < 8; ++nt)
            bfr[nt] = *(const bf16x8*)&W[(size_t)(nt * 16 + l15) * 128 + kc * 32 + quad * 8];
        #pragma unroll
        for (int mt = 0; mt < 2; ++mt)
            #pragma unroll
            for (int nt = 0; nt < 8; ++nt)
                acc[mt][nt] = __builtin_amdgcn_mfma_f32_16x16x32_bf16(af[mt], bfr[nt], acc[mt][nt], 0, 0, 0);
    }
    #pragma unroll
    for (int mt = 0; mt < 2; ++mt)
        #pragma unroll
        for (int r = 0; r < 4; ++r) {
            int m = m0 + w * 32 + mt * 16 + quad * 4 + r;
            #pragma unroll
            for (int nt = 0; nt < 8; ++nt)
                Y[(size_t)m * 128 + nt * 16 + l15] = acc[mt][nt][r];
        }
}

// ---------------------------------------------------------------------------
// One block per (window, head); 512 threads = 8 waves:
// wave = khalf*4 + wq. Wave handles 64 queries (group wq) x 512 keys (half).
// Partials combine additively (no-max softmax is associative).
__global__ __launch_bounds__(512, 4) void halo_attn(
    const ushort_t* __restrict__ QKV,   // [32768][384] bf16 (Q pre-scaled)
    const ushort_t* __restrict__ biasf, // bf16 fragment bias (log2e domain)
    ushort_t* __restrict__ O)           // [32768][128] bf16
{
    __shared__ ushort_t P_lds[8 * 64 * PK];   // 40960 B (also combine buffer)
    __shared__ ushort_t Vt_lds[2 * 32 * VK];  // 9216 B

    const int t     = threadIdx.x;
    const int wave  = t >> 6;
    const int khalf = wave >> 2;
    const int wq    = wave & 3;
    const int lane  = t & 63;
    const int quad  = lane >> 4;
    const int l15   = lane & 15;

    const int win  = blockIdx.x;
    const int head = blockIdx.y;
    const int b    = win >> 6;
    const int wh   = (win >> 3) & 7;
    const int ww   = win & 7;

    // Q B-fragments (persistent)
    bf16x8 qf[4];
    int qpix[4];
    #pragma unroll
    for (int qt = 0; qt < 4; ++qt) {
        int q_abs = wq * 64 + qt * 16 + l15;
        int gy = wh * 16 + (q_abs >> 4), gx = ww * 16 + (q_abs & 15);
        int pix = (b * 128 + gy) * 128 + gx;
        qpix[qt] = pix;
        qf[qt] = *(const bf16x8*)(QKV + (size_t)pix * 384 + head * 32 + quad * 8);
    }

    floatx4 Oa[2][4];
    #pragma unroll
    for (int dt = 0; dt < 2; ++dt)
        #pragma unroll
        for (int qt = 0; qt < 4; ++qt)
            Oa[dt][qt] = (floatx4)0.f;
    float l[4] = {0.f, 0.f, 0.f, 0.f};

    ushort_t* Pw  = P_lds + wave * 64 * PK;
    ushort_t* Vtw = Vt_lds + khalf * 32 * VK;

    for (int c = 0; c < 8; ++c) {
        const int kc_abs = khalf * 8 + c;

        // ---- cooperative Vt staging: wave writes keys wq*16+l15, dims quad*8.. ----
        __syncthreads();
        {
            int key_local = wq * 16 + l15;
            int key = kc_abs * 64 + key_local;
            int ky = reflect_idx(wh * 16 + (key >> 5) - 8);
            int kx = reflect_idx(ww * 16 + (key & 31) - 8);
            int pixv = (b * 128 + ky) * 128 + kx;
            int4 vv = *(const int4*)(QKV + (size_t)pixv * 384 + 256 + head * 32 + quad * 8);
            const ushort_t* vs = (const ushort_t*)&vv;
            #pragma unroll
            for (int i = 0; i < 8; ++i)
                Vtw[(quad * 8 + i) * VK + key_local] = vs[i];
        }
        __syncthreads();

        // ---- K A-fragments ----
        bf16x8 kf[4];
        #pragma unroll
        for (int kt = 0; kt < 4; ++kt) {
            int key = kc_abs * 64 + kt * 16 + l15;
            int ky = reflect_idx(wh * 16 + (key >> 5) - 8);
            int kx = reflect_idx(ww * 16 + (key & 31) - 8);
            int pixk = (b * 128 + ky) * 128 + kx;
            kf[kt] = *(const bf16x8*)(QKV + (size_t)pixk * 384 + 128 + head * 32 + quad * 8);
        }

        // ---- S init from bf16 bias fragments ----
        floatx4 S[4][4];
        #pragma unroll
        for (int kt = 0; kt < 4; ++kt) {
            int kt_abs = kc_abs * 4 + kt;
            #pragma unroll
            for (int qt = 0; qt < 4; ++qt) {
                int qt_abs = wq * 4 + qt;
                uint2 pk = *(const uint2*)(biasf +
                    ((((size_t)head * 64 + kt_abs) * 16 + qt_abs) * 64 + lane) * 4);
                S[kt][qt][0] = __uint_as_float(pk.x << 16);
                S[kt][qt][1] = __uint_as_float(pk.x & 0xffff0000u);
                S[kt][qt][2] = __uint_as_float(pk.y << 16);
                S[kt][qt][3] = __uint_as_float(pk.y & 0xffff0000u);
            }
        }
        #pragma unroll
        for (int kt = 0; kt < 4; ++kt)
            #pragma unroll
            for (int qt = 0; qt < 4; ++qt)
                S[kt][qt] = __builtin_amdgcn_mfma_f32_16x16x32_bf16(kf[kt], qf[qt], S[kt][qt], 0, 0, 0);

        // ---- exp2 + partial l ----
        #pragma unroll
        for (int qt = 0; qt < 4; ++qt) {
            float ls = 0.f;
            #pragma unroll
            for (int kt = 0; kt < 4; ++kt)
                #pragma unroll
                for (int r = 0; r < 4; ++r) {
                    float p = EXP2F(S[kt][qt][r]);
                    S[kt][qt][r] = p;
                    ls += p;
                }
            l[qt] += ls;
        }

        // ---- PV in two 32-key phases through the small P buffer ----
        #pragma unroll
        for (int ks = 0; ks < 2; ++ks) {
            #pragma unroll
            for (int qt = 0; qt < 4; ++qt)
                #pragma unroll
                for (int kh = 0; kh < 2; ++kh) {
                    int kt = ks * 2 + kh;
                    uint2 pk;
                    pk.x = __builtin_amdgcn_perm(__float_as_uint(S[kt][qt][1]),
                                                 __float_as_uint(S[kt][qt][0]), 0x07060302u);
                    pk.y = __builtin_amdgcn_perm(__float_as_uint(S[kt][qt][3]),
                                                 __float_as_uint(S[kt][qt][2]), 0x07060302u);
                    *(uint2*)&Pw[(qt * 16 + l15) * PK + kh * 16 + quad * 4] = pk;
                }
            bf16x8 vf[2];
            #pragma unroll
            for (int dt = 0; dt < 2; ++dt)
                vf[dt] = *(const bf16x8*)&Vtw[(dt * 16 + l15) * VK + ks * 32 + quad * 8];
            #pragma unroll
            for (int qt = 0; qt < 4; ++qt) {
                bf16x8 pf = *(const bf16x8*)&Pw[(qt * 16 + l15) * PK + quad * 8];
                #pragma unroll
                for (int dt = 0; dt < 2; ++dt)
                    Oa[dt][qt] = __builtin_amdgcn_mfma_f32_16x16x32_bf16(vf[dt], pf, Oa[dt][qt], 0, 0, 0);
            }
        }
    }

    // ---- combine key-halves: khalf1 writes partials, khalf0 sums+stores ----
    __syncthreads();
    float* slot = (float*)P_lds + (size_t)(wq * 64 + lane) * 40;
    if (khalf == 1) {
        #pragma unroll
        for (int dt = 0; dt < 2; ++dt)
            #pragma unroll
            for (int qt = 0; qt < 4; ++qt)
                *(floatx4*)(slot + (dt * 4 + qt) * 4) = Oa[dt][qt];
        floatx4 lv = {l[0], l[1], l[2], l[3]};
        *(floatx4*)(slot + 32) = lv;
    }
    __syncthreads();
    if (khalf == 0) {
        #pragma unroll
        for (int dt = 0; dt < 2; ++dt)
            #pragma unroll
            for (int qt = 0; qt < 4; ++qt)
                Oa[dt][qt] += *(const floatx4*)(slot + (dt * 4 + qt) * 4);
        floatx4 lv = *(const floatx4*)(slot + 32);
        #pragma unroll
        for (int qt = 0; qt < 4; ++qt) {
            float lq = l[qt] + lv[qt];
            lq += __shfl_xor(lq, 16);
            lq += __shfl_xor(lq, 32);
            float inv = 1.0f / lq;
            #pragma unroll
            for (int dt = 0; dt < 2; ++dt) {
                uint2 pk;
                pk.x = f2b(Oa[dt][qt][0] * inv) | (f2b(Oa[dt][qt][1] * inv) << 16);
                pk.y = f2b(Oa[dt][qt][2] * inv) | (f2b(Oa[dt][qt][3] * inv) << 16);
                *(uint2*)(O + (size_t)qpix[qt] * 128 + head * 32 + dt * 16 + quad * 4) = pk;
            }
        }
    }
}

// ---------------------------------------------------------------------------
extern "C" void kernel_launch(void* const* d_in, const int* in_sizes, int n_in,
                              void* d_out, int out_size, void* d_ws, size_t ws_size,
                              hipStream_t stream)
{
    const float* x          = (const float*)d_in[0];
    const float* Wq         = (const float*)d_in[1];
    const float* bq         = (const float*)d_in[2];
    const float* Wk         = (const float*)d_in[3];
    const float* bk         = (const float*)d_in[4];
    const float* Wv         = (const float*)d_in[5];
    const float* bv         = (const float*)d_in[6];
    const float* Wp         = (const float*)d_in[7];
    const float* bp         = (const float*)d_in[8];
    const float* bias_table = (const float*)d_in[9];
    float* out = (float*)d_out;

    const int M = 2 * 128 * 128; // 32768 pixels
    char* ws = (char*)d_ws;
    ushort_t* Wqkv  = (ushort_t*)(ws);                    // 98304 B
    ushort_t* Wpb   = (ushort_t*)(ws + 98304);            // 32768 B
    float*    bqkv  = (float*)   (ws + 131072);           // 1536 B
    float*    bpb   = (float*)   (ws + 132608);           // 512 B
    ushort_t* QKV   = (ushort_t*)(ws + 133120);           // 25165824 B
    ushort_t* Ob    = (ushort_t*)(ws + 25298944);         // 8388608 B
    ushort_t* biasf = (ushort_t*)(ws + 33687552);         // 8388608 B

    pack_w<<<dim3(257), dim3(256), 0, stream>>>(Wq, Wk, Wv, Wp, bq, bk, bv, bp,
                                                Wqkv, Wpb, bqkv, bpb);
    bias_frag<<<dim3(16384), dim3(256), 0, stream>>>(bias_table, biasf);
    gemm_qkv<<<dim3(256), dim3(256), 0, stream>>>(x, Wqkv, bqkv, QKV);
    halo_attn<<<dim3(128, NHEADS), dim3(512), 0, stream>>>(QKV, biasf, Ob);
    gemm_proj<<<dim3(256), dim3(256), 0, stream>>>(Ob, Wpb, bpb, out);
}

// Round 7
// 195.360 us; speedup vs baseline: 1.1857x; 1.1857x over previous
//
#include <hip/hip_runtime.h>

// HaloAttention. B=2, H=W=128, C=128, NH=4, hd=32, WS=16, HS=8, WSH=32.
// R7: query-split attention (grid 256x4, 4 waves x 32 queries, no combine),
// shared Vt staging, phased 32-key P LDS, bf16 bias frags (2 MB, exact grid),
// exp2-domain softmax, 64-row-tile GEMMs with 6 blocks/CU.

typedef unsigned short ushort_t;
typedef __attribute__((ext_vector_type(8))) short bf16x8;
typedef __attribute__((ext_vector_type(4))) float floatx4;

#define NHEADS 4
#define BTBL 2209          // 47*47 bias table rows
#define PK 40              // P stride (bf16): 32 keys + 8 pad
#define VK 72              // Vt stride (bf16): 64 keys + 8 pad
// 2^-1.5 * log2(e)  (q scale folded with exp2-domain conversion)
#define QS_LOG2E 0.2550348635f
#define LOG2E 1.4426950408889634f

#if __has_builtin(__builtin_amdgcn_exp2f)
#define EXP2F(x) __builtin_amdgcn_exp2f(x)
#else
#define EXP2F(x) __expf((x) * 0.6931471805599453f)
#endif

__device__ __forceinline__ int reflect_idx(int p) {
    p = (p < 0) ? -p : p;
    p = (p > 127) ? 254 - p : p;
    return p;
}

// fp32 -> bf16 bits, RNE
__device__ __forceinline__ unsigned f2b(float x) {
    unsigned u = __float_as_uint(x);
    return (u + 0x7fffu + ((u >> 16) & 1u)) >> 16;
}

// ---------------------------------------------------------------------------
__global__ __launch_bounds__(256) void pack_w(
    const float* __restrict__ Wq, const float* __restrict__ Wk,
    const float* __restrict__ Wv, const float* __restrict__ Wp,
    const float* __restrict__ bq, const float* __restrict__ bk,
    const float* __restrict__ bv, const float* __restrict__ bp,
    ushort_t* __restrict__ Wqkv, ushort_t* __restrict__ Wpb,
    float* __restrict__ bqkv, float* __restrict__ bpb)
{
    int idx = blockIdx.x * 256 + threadIdx.x;
    if (idx < 16384)       Wqkv[idx] = (ushort_t)f2b(Wq[idx]);
    else if (idx < 32768)  Wqkv[idx] = (ushort_t)f2b(Wk[idx - 16384]);
    else if (idx < 49152)  Wqkv[idx] = (ushort_t)f2b(Wv[idx - 32768]);
    else if (idx < 65536)  Wpb[idx - 49152] = (ushort_t)f2b(Wp[idx - 49152]);
    else {
        int e = idx - 65536;
        for (int k = e; k < 512; k += 256) {
            if (k < 128)      bqkv[k] = bq[k];
            else if (k < 256) bqkv[k] = bk[k - 128];
            else if (k < 384) bqkv[k] = bv[k - 256];
            else              bpb[k - 384] = bp[k - 384];
        }
    }
}

// ---------------------------------------------------------------------------
// Bias fragments bf16, pre-multiplied by log2(e):
// layout [h 4][kt 64][qt 16][lane 64][reg 4]. Exactly 1,048,576 entries.
__global__ __launch_bounds__(256) void bias_frag(
    const float* __restrict__ bt, ushort_t* __restrict__ bf)
{
    int idx = blockIdx.x * 256 + threadIdx.x;   // grid 4096 -> 1,048,576
    int reg  = idx & 3;
    int lane = (idx >> 2) & 63;
    int qt   = (idx >> 8) & 15;
    int kt   = (idx >> 12) & 63;
    int h    = idx >> 18;                       // 0..3
    int key  = kt * 16 + ((lane >> 4) << 2) + reg;
    int q    = qt * 16 + (lane & 15);
    int kr = key >> 5, kc = key & 31;
    int bidx = ((q >> 5) + 31 - kr) * 47 + (q & 31) - kc + 23;
    if (bidx < 0) bidx += BTBL;
    bf[idx] = (ushort_t)f2b(bt[bidx * NHEADS + h] * LOG2E);
}

// ---------------------------------------------------------------------------
// QKV GEMM, 64-row tiles, grid (512, 3). Q block (nb==0) scaled.
__global__ __launch_bounds__(256) void gemm_qkv(
    const float* __restrict__ X, const ushort_t* __restrict__ W,
    const float* __restrict__ bias, ushort_t* __restrict__ Y)
{
    __shared__ ushort_t Xs[64 * 136];

    const int t    = threadIdx.x;
    const int wq   = t >> 6;
    const int lane = t & 63;
    const int quad = lane >> 4;
    const int l15  = lane & 15;
    const int m0   = blockIdx.x * 64;
    const int nb   = blockIdx.y;
    const float sc = (nb == 0) ? QS_LOG2E : 1.0f;

    #pragma unroll
    for (int i = 0; i < 8; ++i) {
        int s = t + i * 256;
        int row = s >> 5, c4 = s & 31;
        float4 v = *(const float4*)&X[(size_t)(m0 + row) * 128 + c4 * 4];
        uint2 pk;
        pk.x = f2b(v.x) | (f2b(v.y) << 16);
        pk.y = f2b(v.z) | (f2b(v.w) << 16);
        *(uint2*)&Xs[row * 136 + c4 * 4] = pk;
    }
    __syncthreads();

    floatx4 acc[8];
    #pragma unroll
    for (int nt = 0; nt < 8; ++nt)
        acc[nt] = (floatx4)(bias[nb * 128 + nt * 16 + l15]);

    #pragma unroll
    for (int kc = 0; kc < 4; ++kc) {
        bf16x8 af = *(const bf16x8*)&Xs[(wq * 16 + l15) * 136 + kc * 32 + quad * 8];
        #pragma unroll
        for (int nt = 0; nt < 8; ++nt) {
            bf16x8 bfr = *(const bf16x8*)&W[(size_t)(nb * 128 + nt * 16 + l15) * 128 + kc * 32 + quad * 8];
            acc[nt] = __builtin_amdgcn_mfma_f32_16x16x32_bf16(af, bfr, acc[nt], 0, 0, 0);
        }
    }

    #pragma unroll
    for (int r = 0; r < 4; ++r) {
        int m = m0 + wq * 16 + quad * 4 + r;
        #pragma unroll
        for (int nt = 0; nt < 8; ++nt)
            Y[(size_t)m * 384 + nb * 128 + nt * 16 + l15] = (ushort_t)f2b(acc[nt][r] * sc);
    }
}

// ---------------------------------------------------------------------------
// Projection GEMM, 64-row tiles, grid (512). bf16 in, fp32 out.
__global__ __launch_bounds__(256) void gemm_proj(
    const ushort_t* __restrict__ X, const ushort_t* __restrict__ W,
    const float* __restrict__ bias, float* __restrict__ Y)
{
    __shared__ ushort_t Xs[64 * 136];

    const int t    = threadIdx.x;
    const int wq   = t >> 6;
    const int lane = t & 63;
    const int quad = lane >> 4;
    const int l15  = lane & 15;
    const int m0   = blockIdx.x * 64;

    #pragma unroll
    for (int i = 0; i < 4; ++i) {
        int s = t + i * 256;
        int row = s >> 4, c8 = s & 15;
        *(int4*)&Xs[row * 136 + c8 * 8] = *(const int4*)&X[(size_t)(m0 + row) * 128 + c8 * 8];
    }
    __syncthreads();

    floatx4 acc[8];
    #pragma unroll
    for (int nt = 0; nt < 8; ++nt)
        acc[nt] = (floatx4)(bias[nt * 16 + l15]);

    #pragma unroll
    for (int kc = 0; kc < 4; ++kc) {
        bf16x8 af = *(const bf16x8*)&Xs[(wq * 16 + l15) * 136 + kc * 32 + quad * 8];
        #pragma unroll
        for (int nt = 0; nt < 8; ++nt) {
            bf16x8 bfr = *(const bf16x8*)&W[(size_t)(nt * 16 + l15) * 128 + kc * 32 + quad * 8];
            acc[nt] = __builtin_amdgcn_mfma_f32_16x16x32_bf16(af, bfr, acc[nt], 0, 0, 0);
        }
    }

    #pragma unroll
    for (int r = 0; r < 4; ++r) {
        int m = m0 + wq * 16 + quad * 4 + r;
        #pragma unroll
        for (int nt = 0; nt < 8; ++nt)
            Y[(size_t)m * 128 + nt * 16 + l15] = acc[nt][r];
    }
}

// ---------------------------------------------------------------------------
// Attention: block = (win, qhalf, head); 4 waves x 32 queries, all 1024 keys.
// Grid 256 x 4 = 1024 blocks. No-max softmax (|logits| < 1), exp2 domain.
__global__ __launch_bounds__(256, 2) void halo_attn(
    const ushort_t* __restrict__ QKV,   // [32768][384] bf16 (Q pre-scaled)
    const ushort_t* __restrict__ biasf, // bf16 fragment bias (log2e domain)
    ushort_t* __restrict__ O)           // [32768][128] bf16
{
    __shared__ ushort_t Vt_lds[32 * VK];     // 4608 B, shared by all 4 waves
    __shared__ ushort_t P_lds[4 * 32 * PK];  // 10240 B, per-wave slices

    const int t    = threadIdx.x;
    const int wq   = t >> 6;
    const int lane = t & 63;
    const int quad = lane >> 4;
    const int l15  = lane & 15;

    const int bx    = blockIdx.x;        // 0..255
    const int win   = bx >> 1;
    const int qhalf = bx & 1;
    const int head  = blockIdx.y;
    const int b     = win >> 6;
    const int wh    = (win >> 3) & 7;
    const int ww    = win & 7;

    // Q B-fragments: 2 tiles of 16 queries
    bf16x8 qf[2];
    int qpix[2];
    #pragma unroll
    for (int qt = 0; qt < 2; ++qt) {
        int q_abs = qhalf * 128 + wq * 32 + qt * 16 + l15;
        int gy = wh * 16 + (q_abs >> 4), gx = ww * 16 + (q_abs & 15);
        int pix = (b * 128 + gy) * 128 + gx;
        qpix[qt] = pix;
        qf[qt] = *(const bf16x8*)(QKV + (size_t)pix * 384 + head * 32 + quad * 8);
    }

    floatx4 Oa[2][2];
    #pragma unroll
    for (int dt = 0; dt < 2; ++dt)
        #pragma unroll
        for (int qt = 0; qt < 2; ++qt)
            Oa[dt][qt] = (floatx4)0.f;
    float l[2] = {0.f, 0.f};

    ushort_t* Pw = P_lds + wq * 32 * PK;
    const int key_local = wq * 16 + l15;

    for (int c = 0; c < 16; ++c) {
        // ---- cooperative Vt staging (all 256 threads) ----
        __syncthreads();
        {
            int key = c * 64 + key_local;
            int ky = reflect_idx(wh * 16 + (key >> 5) - 8);
            int kx = reflect_idx(ww * 16 + (key & 31) - 8);
            int pixv = (b * 128 + ky) * 128 + kx;
            int4 vv = *(const int4*)(QKV + (size_t)pixv * 384 + 256 + head * 32 + quad * 8);
            const ushort_t* vs = (const ushort_t*)&vv;
            #pragma unroll
            for (int i = 0; i < 8; ++i)
                Vt_lds[(quad * 8 + i) * VK + key_local] = vs[i];
        }
        __syncthreads();

        // ---- K A-fragments ----
        bf16x8 kf[4];
        #pragma unroll
        for (int kt = 0; kt < 4; ++kt) {
            int key = c * 64 + kt * 16 + l15;
            int ky = reflect_idx(wh * 16 + (key >> 5) - 8);
            int kx = reflect_idx(ww * 16 + (key & 31) - 8);
            int pixk = (b * 128 + ky) * 128 + kx;
            kf[kt] = *(const bf16x8*)(QKV + (size_t)pixk * 384 + 128 + head * 32 + quad * 8);
        }

        // ---- S init from bf16 bias fragments ----
        floatx4 S[4][2];
        #pragma unroll
        for (int kt = 0; kt < 4; ++kt) {
            int kt_abs = c * 4 + kt;
            #pragma unroll
            for (int qt = 0; qt < 2; ++qt) {
                int qt_abs = qhalf * 8 + wq * 2 + qt;
                uint2 pk = *(const uint2*)(biasf +
                    ((((size_t)head * 64 + kt_abs) * 16 + qt_abs) * 64 + lane) * 4);
                S[kt][qt][0] = __uint_as_float(pk.x << 16);
                S[kt][qt][1] = __uint_as_float(pk.x & 0xffff0000u);
                S[kt][qt][2] = __uint_as_float(pk.y << 16);
                S[kt][qt][3] = __uint_as_float(pk.y & 0xffff0000u);
            }
        }
        #pragma unroll
        for (int kt = 0; kt < 4; ++kt)
            #pragma unroll
            for (int qt = 0; qt < 2; ++qt)
                S[kt][qt] = __builtin_amdgcn_mfma_f32_16x16x32_bf16(kf[kt], qf[qt], S[kt][qt], 0, 0, 0);

        // ---- exp2 + partial l ----
        #pragma unroll
        for (int qt = 0; qt < 2; ++qt) {
            float ls = 0.f;
            #pragma unroll
            for (int kt = 0; kt < 4; ++kt)
                #pragma unroll
                for (int r = 0; r < 4; ++r) {
                    float p = EXP2F(S[kt][qt][r]);
                    S[kt][qt][r] = p;
                    ls += p;
                }
            l[qt] += ls;
        }

        // ---- PV in two 32-key phases through per-wave P buffer ----
        #pragma unroll
        for (int ks = 0; ks < 2; ++ks) {
            #pragma unroll
            for (int qt = 0; qt < 2; ++qt)
                #pragma unroll
                for (int kh = 0; kh < 2; ++kh) {
                    int kt = ks * 2 + kh;
                    uint2 pk;
                    pk.x = __builtin_amdgcn_perm(__float_as_uint(S[kt][qt][1]),
                                                 __float_as_uint(S[kt][qt][0]), 0x07060302u);
                    pk.y = __builtin_amdgcn_perm(__float_as_uint(S[kt][qt][3]),
                                                 __float_as_uint(S[kt][qt][2]), 0x07060302u);
                    *(uint2*)&Pw[(qt * 16 + l15) * PK + kh * 16 + quad * 4] = pk;
                }
            bf16x8 vf[2];
            #pragma unroll
            for (int dt = 0; dt < 2; ++dt)
                vf[dt] = *(const bf16x8*)&Vt_lds[(dt * 16 + l15) * VK + ks * 32 + quad * 8];
            #pragma unroll
            for (int qt = 0; qt < 2; ++qt) {
                bf16x8 pf = *(const bf16x8*)&Pw[(qt * 16 + l15) * PK + quad * 8];
                #pragma unroll
                for (int dt = 0; dt < 2; ++dt)
                    Oa[dt][qt] = __builtin_amdgcn_mfma_f32_16x16x32_bf16(vf[dt], pf, Oa[dt][qt], 0, 0, 0);
            }
        }
    }

    // ---- epilogue: reduce l across quads, normalize, bf16 store ----
    #pragma unroll
    for (int qt = 0; qt < 2; ++qt) {
        float lq = l[qt];
        lq += __shfl_xor(lq, 16);
        lq += __shfl_xor(lq, 32);
        float inv = 1.0f / lq;
        #pragma unroll
        for (int dt = 0; dt < 2; ++dt) {
            uint2 pk;
            pk.x = f2b(Oa[dt][qt][0] * inv) | (f2b(Oa[dt][qt][1] * inv) << 16);
            pk.y = f2b(Oa[dt][qt][2] * inv) | (f2b(Oa[dt][qt][3] * inv) << 16);
            *(uint2*)(O + (size_t)qpix[qt] * 128 + head * 32 + dt * 16 + quad * 4) = pk;
        }
    }
}

// ---------------------------------------------------------------------------
extern "C" void kernel_launch(void* const* d_in, const int* in_sizes, int n_in,
                              void* d_out, int out_size, void* d_ws, size_t ws_size,
                              hipStream_t stream)
{
    const float* x          = (const float*)d_in[0];
    const float* Wq         = (const float*)d_in[1];
    const float* bq         = (const float*)d_in[2];
    const float* Wk         = (const float*)d_in[3];
    const float* bk         = (const float*)d_in[4];
    const float* Wv         = (const float*)d_in[5];
    const float* bv         = (const float*)d_in[6];
    const float* Wp         = (const float*)d_in[7];
    const float* bp         = (const float*)d_in[8];
    const float* bias_table = (const float*)d_in[9];
    float* out = (float*)d_out;

    char* ws = (char*)d_ws;
    ushort_t* Wqkv  = (ushort_t*)(ws);                    // 98304 B
    ushort_t* Wpb   = (ushort_t*)(ws + 98304);            // 32768 B
    float*    bqkv  = (float*)   (ws + 131072);           // 1536 B
    float*    bpb   = (float*)   (ws + 132608);           // 512 B
    ushort_t* QKV   = (ushort_t*)(ws + 133120);           // 25165824 B
    ushort_t* Ob    = (ushort_t*)(ws + 25298944);         // 8388608 B
    ushort_t* biasf = (ushort_t*)(ws + 33687552);         // 2097152 B

    pack_w<<<dim3(257), dim3(256), 0, stream>>>(Wq, Wk, Wv, Wp, bq, bk, bv, bp,
                                                Wqkv, Wpb, bqkv, bpb);
    bias_frag<<<dim3(4096), dim3(256), 0, stream>>>(bias_table, biasf);
    gemm_qkv<<<dim3(512, 3), dim3(256), 0, stream>>>(x, Wqkv, bqkv, QKV);
    halo_attn<<<dim3(256, NHEADS), dim3(256), 0, stream>>>(QKV, biasf, Ob);
    gemm_proj<<<dim3(512), dim3(256), 0, stream>>>(Ob, Wpb, bpb, out);
}